// Round 14
// baseline (163.926 us; speedup 1.0000x reference)
//
#include <hip/hip_runtime.h>
#include <stdint.h>

typedef unsigned short u16;
typedef _Float16 f16;
typedef _Float16 f16x8 __attribute__((ext_vector_type(8)));
typedef float f32x4 __attribute__((ext_vector_type(4)));

#define DIN 1024
#define SEQ 2048
#define NB 4
#define MB (1u << 20)

// ---------- helpers ----------

__device__ __forceinline__ void gload_lds16(const void* g, void* l) {
    __builtin_amdgcn_global_load_lds(
        (__attribute__((address_space(1))) void*)(uintptr_t)g,
        (__attribute__((address_space(3))) void*)l,
        16, 0, 0);
}

__device__ __forceinline__ int xcd_swz(int h, int cpx) {
    return (h & 7) * cpx + (h >> 3);
}

__device__ __forceinline__ void barrier_raw() {
    asm volatile("" ::: "memory");
    __builtin_amdgcn_s_barrier();
    asm volatile("" ::: "memory");
}
template<int N>
__device__ __forceinline__ void wait_lgkm() {
    asm volatile("s_waitcnt lgkmcnt(%0)" :: "i"(N) : "memory");
    __builtin_amdgcn_sched_barrier(0);
}
template<int N>
__device__ __forceinline__ void wait_vm() {
    asm volatile("s_waitcnt vmcnt(%0)" :: "i"(N) : "memory");
}
#define SB0 __builtin_amdgcn_sched_barrier(0)

// ---------- 8-phase 256x256 GEMM mainloop, full 1-phase-ahead reads ----
// r13 measured: same-phase lgkm waits serialize LDS reads with MFMA
// (5775 cyc/K-tile ~ reads 2300 + MFMA 2500 + barriers). This version
// issues EVERY fragment read >=1 phase before its MFMA consumes it, so
// the LDS pipe drains under the matrix pipe. Barrier/stage/vmcnt
// protocol is UNCHANGED from the refcheck-proven r9 ledger.
// Per-tile FIFO ledger (ds, per wave):
//  ph4(t-1): a0(t)x8, b01(t)x4 issued
//  ph1(t): +b23x4,+a1a x4 -> lgkm(8) drains a0,b01 -> MM a0 x b01
//  ph2(t): +a1b x4         -> lgkm(8) drains b23   -> MM a0 x b23
//  ph3(t): stage B(t+2); vm(4) [drains A(t+1)];
//                             lgkm(0) drains a1    -> MM a1 x b01
//  ph4(t): read a0(t+1),b01(t+1) [resident per ph3 vm+barrier];
//          stage A(t+2);      no wait              -> MM a1 x b23
// t=nt-1's ph4 reads stale LDS into regs never consumed (harmless).

__device__ __forceinline__ void gemm256(
    const char* __restrict__ A, const char* __restrict__ B,
    int ldab, int ldbb, int nt, char* smem, f32x4 acc[8][4])
{
    const int tid  = threadIdx.x;
    const int lane = tid & 63;
    const int wave = tid >> 6;
    const int ln15 = lane & 15;
    const int k16  = (lane >> 4) << 4;
    const int wmB  = (wave >> 2) * 128;
    const int wnB  = (wave & 3) * 64;

    #pragma unroll
    for (int m = 0; m < 8; ++m)
        #pragma unroll
        for (int n = 0; n < 4; ++n)
            acc[m][n] = (f32x4){0.f, 0.f, 0.f, 0.f};

    const char* pA[2];
    const char* pB[2];
    #pragma unroll
    for (int i = 0; i < 2; ++i) {
        const int La = i * 8192 + tid * 16;
        const int r  = La >> 7;
        const int sc = (La & 127) ^ ((r & 7) << 4);
        pA[i] = A + (size_t)r * ldab + sc;
        pB[i] = B + (size_t)r * ldbb + sc;
    }
    const int ldsw = wave * 1024;

    f16x8 a0[4][2], a1[4][2], b[4][2];

    auto stage = [&](int g) {
        if (g < 4 * nt) {
            const int ks  = g >> 2;
            const int isB = ((g & 2) == 0);
            const int h   = g & 1;
            char* l = smem + (ks & 1) * 65536 + (isB ? 32768 : 0) + h * 16384 + ldsw;
            #pragma unroll
            for (int i = 0; i < 2; ++i) {
                const char* gp = (isB ? pB[i] + (size_t)(h * 128) * ldbb
                                      : pA[i] + (size_t)(h * 128) * ldab) + ks * 128;
                gload_lds16(gp, l + i * 8192);
            }
        }
    };

#define RDA0(base) { _Pragma("unroll") for (int mf = 0; mf < 4; ++mf) { \
        const int r = wmB + mf * 16 + ln15; \
        const int sw = (r & 7) << 4; \
        const char* p = (base) + r * 128; \
        a0[mf][0] = *(const f16x8*)(p + (k16 ^ sw)); \
        a0[mf][1] = *(const f16x8*)(p + ((64 + k16) ^ sw)); } }

#define RDA1H(base, mf0) { _Pragma("unroll") for (int mf = (mf0); mf < (mf0) + 2; ++mf) { \
        const int r = wmB + (mf + 4) * 16 + ln15; \
        const int sw = (r & 7) << 4; \
        const char* p = (base) + r * 128; \
        a1[mf][0] = *(const f16x8*)(p + (k16 ^ sw)); \
        a1[mf][1] = *(const f16x8*)(p + ((64 + k16) ^ sw)); } }

#define RDB2(nf0, base) { _Pragma("unroll") for (int nf = (nf0); nf < (nf0) + 2; ++nf) { \
        const int r = wnB + nf * 16 + ln15; \
        const int sw = (r & 7) << 4; \
        const char* p = (base) + r * 128; \
        b[nf][0] = *(const f16x8*)(p + (k16 ^ sw)); \
        b[nf][1] = *(const f16x8*)(p + ((64 + k16) ^ sw)); } }

#define MM(aa, aoff, nf0) { __builtin_amdgcn_s_setprio(1); \
        _Pragma("unroll") for (int mf = 0; mf < 4; ++mf) \
        _Pragma("unroll") for (int nf = (nf0); nf < (nf0) + 2; ++nf) { \
            acc[(aoff) + mf][nf] = __builtin_amdgcn_mfma_f32_16x16x32_f16( \
                aa[mf][0], b[nf][0], acc[(aoff) + mf][nf], 0, 0, 0); \
            acc[(aoff) + mf][nf] = __builtin_amdgcn_mfma_f32_16x16x32_f16( \
                aa[mf][1], b[nf][1], acc[(aoff) + mf][nf], 0, 0, 0); } \
        __builtin_amdgcn_s_setprio(0); }

    // prologue: stage tiles 0,1; tile-0 resident; preload a0(0)+b01(0)
    // (mirrors steady-state ph4 so the first ph1's lgkm(8) ledger holds).
    #pragma unroll
    for (int g = 0; g < 8; ++g) stage(g);
    wait_vm<8>();
    barrier_raw();
    RDA0(smem); SB0;
    RDB2(0, smem + 32768); SB0;

    for (int t = 0; t < nt; ++t) {
        const char* sAc = smem + (t & 1) * 65536;
        const char* sBc = sAc + 32768;
        const char* sAn = smem + ((t + 1) & 1) * 65536;
        const char* sBn = sAn + 32768;
        const int gb = 4 * (t + 2);

        // ph1: issue b23(t), a1-half-a(t); MM a0 x b01 (loaded ph4(t-1))
        RDB2(2, sBc); SB0;
        RDA1H(sAc, 0); SB0;
        barrier_raw(); wait_lgkm<8>(); MM(a0, 0, 0); barrier_raw();

        // ph2: issue a1-half-b(t); MM a0 x b23 (b23 drained by lgkm(8))
        RDA1H(sAc, 2); SB0;
        barrier_raw(); wait_lgkm<8>(); MM(a0, 0, 2); barrier_raw();

        // ph3: stage B(t+2); counted vmcnt makes tile t+1 resident
        stage(gb + 0); stage(gb + 1);
        if (t < nt - 2) { wait_vm<4>(); } else if (t == nt - 2) { wait_vm<0>(); }
        barrier_raw(); wait_lgkm<0>(); MM(a1, 4, 0); barrier_raw();

        // ph4: preload a0(t+1), b01(t+1); stage A(t+2); MM a1 x b23, no wait
        RDA0(sAn); SB0;
        RDB2(0, sBn); SB0;
        stage(gb + 2); stage(gb + 3);
        barrier_raw(); MM(a1, 4, 2); barrier_raw();
    }
#undef RDA0
#undef RDA1H
#undef RDB2
#undef MM
}

// ---------- 128x128 2-phase mainloop (V-proj + PV) ----------

__device__ __forceinline__ void gemm_tile(
    const char* __restrict__ A, const char* __restrict__ B,
    int lda, int ldb, int ksteps, char* smem, f32x4 acc[4][4])
{
    const int lane = threadIdx.x & 63;
    const int wave = threadIdx.x >> 6;

    #pragma unroll
    for (int m = 0; m < 4; ++m)
        #pragma unroll
        for (int n = 0; n < 4; ++n)
            acc[m][n] = (f32x4){0.f, 0.f, 0.f, 0.f};

    const char* ga[4];
    const char* gb[4];
    int ldsoff[4];
    #pragma unroll
    for (int i = 0; i < 4; ++i) {
        int La = (wave * 4 + i) * 1024 + lane * 16;
        int r  = La >> 7;
        int cb = La & 127;
        int sc = cb ^ ((r & 7) << 4);
        ga[i] = A + (size_t)r * (size_t)(lda * 2) + sc;
        gb[i] = B + (size_t)r * (size_t)(ldb * 2) + sc;
        ldsoff[i] = (wave * 4 + i) * 1024;
    }

    const int wr = (wave >> 1) * 64;
    const int wc = (wave & 1) * 64;

    for (int ks = 0; ks < ksteps; ++ks) {
        #pragma unroll
        for (int i = 0; i < 4; ++i) {
            gload_lds16(ga[i], smem + ldsoff[i]);
            gload_lds16(gb[i], smem + 16384 + ldsoff[i]);
            ga[i] += 128;
            gb[i] += 128;
        }
        __syncthreads();

        #pragma unroll
        for (int kk = 0; kk < 2; ++kk) {
            const int kb = kk * 64 + ((lane >> 4) << 4);
            f16x8 af[4], bfv[4];
            #pragma unroll
            for (int m = 0; m < 4; ++m) {
                int r = wr + m * 16 + (lane & 15);
                af[m] = *(const f16x8*)(smem + r * 128 + (kb ^ ((r & 7) << 4)));
            }
            #pragma unroll
            for (int n = 0; n < 4; ++n) {
                int r = wc + n * 16 + (lane & 15);
                bfv[n] = *(const f16x8*)(smem + 16384 + r * 128 + (kb ^ ((r & 7) << 4)));
            }
            #pragma unroll
            for (int m = 0; m < 4; ++m)
                #pragma unroll
                for (int n = 0; n < 4; ++n)
                    acc[m][n] = __builtin_amdgcn_mfma_f32_16x16x32_f16(
                        af[m], bfv[n], acc[m][n], 0, 0, 0);
        }
        __syncthreads();
    }
}

// ---------- kernels ----------

// Merged prep: blocks [0,2048) convert x fp32->f16; blocks [2048,5120)
// transpose+convert the three W matrices into wt [3*1024(n)][1024(k)] f16.
__global__ __launch_bounds__(256) void k_prep(
    const float* __restrict__ x, f16* __restrict__ xh,
    const float* __restrict__ Wq, const float* __restrict__ Wk,
    const float* __restrict__ Wv, f16* __restrict__ wt)
{
    __shared__ float tile[32][33];
    const int bid = blockIdx.x;
    if (bid < 2048) {
        const int n8 = (NB * SEQ * DIN) / 8;
        for (int idx = bid * 256 + threadIdx.x; idx < n8; idx += 2048 * 256) {
            f32x4 a = ((const f32x4*)x)[(size_t)idx * 2];
            f32x4 b = ((const f32x4*)x)[(size_t)idx * 2 + 1];
            f16x8 o;
            o[0] = (f16)a[0]; o[1] = (f16)a[1]; o[2] = (f16)a[2]; o[3] = (f16)a[3];
            o[4] = (f16)b[0]; o[5] = (f16)b[1]; o[6] = (f16)b[2]; o[7] = (f16)b[3];
            ((f16x8*)xh)[idx] = o;
        }
    } else {
        const int wb = bid - 2048;          // 0..3071
        const int mtx = wb >> 10;           // 0..2
        const int rem = wb & 1023;
        const int n0 = (rem & 31) * 32, k0 = (rem >> 5) * 32;
        const float* W = (mtx == 0) ? Wq : (mtx == 1 ? Wk : Wv);
        const int c = threadIdx.x & 31, r0 = threadIdx.x >> 5;
        #pragma unroll
        for (int rr = r0; rr < 32; rr += 8)
            tile[rr][c] = W[(size_t)(k0 + rr) * DIN + n0 + c];
        __syncthreads();
        f16* o = wt + (size_t)mtx * DIN * DIN;
        #pragma unroll
        for (int rr = r0; rr < 32; rr += 8)
            o[(size_t)(n0 + rr) * DIN + k0 + c] = (f16)tile[c][rr];
    }
}

// Q|K = x @ W^T + bias, 8-phase 256x256, grid 32x8 = 256 (tail-free).
__global__ __launch_bounds__(512, 2) void k_gemm_qk8(
    const f16* __restrict__ xh, const f16* __restrict__ wt,
    const float* __restrict__ bq, const float* __restrict__ bk,
    f16* __restrict__ Q, f16* __restrict__ K)
{
    extern __shared__ char smem[];
    f32x4 acc[8][4];
    const int sid = xcd_swz(blockIdx.x, 32);   // 256 blocks, %8==0
    const int blkN = sid & 7;                  // 0..7  (256-col tiles over Q|K)
    const int blkM = sid >> 3;                 // 0..31
    gemm256((const char*)(xh + (size_t)blkM * 256 * DIN),
            (const char*)(wt + (size_t)blkN * 256 * DIN),
            DIN * 2, DIN * 2, DIN / 64, smem, acc);

    const int lane = threadIdx.x & 63;
    const int wave = threadIdx.x >> 6;
    const int row0 = blkM * 256 + (wave >> 2) * 128;
    const int col0 = blkN * 256 + (wave & 3) * 64;   // wave-uniform matrix id

    f16* dst = (col0 < 1024) ? Q : K;
    const float* bsrc = (col0 < 1024) ? bq : bk;
    const int ncb = col0 & 1023;
    #pragma unroll
    for (int n = 0; n < 4; ++n) {
        int nc = ncb + n * 16 + (lane & 15);
        float bias = bsrc[nc];
        #pragma unroll
        for (int m = 0; m < 8; ++m) {
            #pragma unroll
            for (int j = 0; j < 4; ++j) {
                int row = row0 + m * 16 + (lane >> 4) * 4 + j;
                dst[(size_t)row * 1024 + nc] = (f16)(acc[m][n][j] + bias);
            }
        }
    }
}

// V = x @ Wv^T + bias, 128x128 2-phase, written TRANSPOSED into Vt[b][d][s].
__global__ __launch_bounds__(256) void k_gemm_v(
    const f16* __restrict__ xh, const f16* __restrict__ wtv,
    const float* __restrict__ bv, f16* __restrict__ Vt)
{
    __shared__ __align__(16) char smem[32768];
    f32x4 acc[4][4];
    const int sid = xcd_swz(blockIdx.x, 64);   // 512 blocks, %8==0
    const int blkN = sid & 7;                  // 0..7   (V cols)
    const int blkM = sid >> 3;                 // 0..63
    gemm_tile((const char*)(xh  + (size_t)blkM * 128 * DIN),
              (const char*)(wtv + (size_t)blkN * 128 * DIN),
              DIN, DIN, DIN / 64, smem, acc);

    const int lane = threadIdx.x & 63;
    const int wave = threadIdx.x >> 6;
    const int row0 = blkM * 128 + (wave >> 1) * 64;
    const int col0 = blkN * 128 + (wave & 1) * 64;
    const int bb = row0 >> 11;
    const int sb = row0 & (SEQ - 1);
    f16* Vtb = Vt + (size_t)bb * DIN * SEQ;
    #pragma unroll
    for (int n = 0; n < 4; ++n) {
        int d = col0 + n * 16 + (lane & 15);
        float bias = bv[d];
        #pragma unroll
        for (int m = 0; m < 4; ++m) {
            #pragma unroll
            for (int j = 0; j < 4; ++j) {
                int s = sb + m * 16 + (lane >> 4) * 4 + j;
                Vtb[(size_t)d * SEQ + s] = (f16)(acc[m][n][j] + bias);
            }
        }
    }
}

// scores[b] = Q[b] @ K[b]^T, 8-phase 256x256 -> f16 S (unscaled).
__global__ __launch_bounds__(512, 2) void k_gemm_scores8(
    const f16* __restrict__ Q, const f16* __restrict__ K, f16* __restrict__ S)
{
    extern __shared__ char smem[];
    f32x4 acc[8][4];
    const int sid = xcd_swz(blockIdx.x, 32);   // 256 blocks, %8==0
    const int bx = sid & 7, by = (sid >> 3) & 7, b = sid >> 6;
    const f16* Qb = Q + (size_t)b * SEQ * DIN;
    const f16* Kb = K + (size_t)b * SEQ * DIN;
    gemm256((const char*)(Qb + (size_t)by * 256 * DIN),
            (const char*)(Kb + (size_t)bx * 256 * DIN),
            DIN * 2, DIN * 2, DIN / 64, smem, acc);

    f16* Sb = S + (size_t)b * SEQ * SEQ;
    const int lane = threadIdx.x & 63;
    const int wave = threadIdx.x >> 6;
    const int row0 = by * 256 + (wave >> 2) * 128;
    const int col0 = bx * 256 + (wave & 3) * 64;
    #pragma unroll
    for (int m = 0; m < 8; ++m)
        #pragma unroll
        for (int n = 0; n < 4; ++n) {
            int col = col0 + n * 16 + (lane & 15);
            #pragma unroll
            for (int j = 0; j < 4; ++j) {
                int row = row0 + m * 16 + (lane >> 4) * 4 + j;
                Sb[(size_t)row * SEQ + col] = (f16)acc[m][n][j];
            }
        }
}

// row softmax: one block per row, 2048 f16 in -> 2048 f16 out, /32 folded.
__global__ __launch_bounds__(256) void k_softmax(
    const f16* __restrict__ S, f16* __restrict__ P)
{
    const size_t row = blockIdx.x;
    const f16* s = S + row * SEQ;
    f16* p = P + row * SEQ;
    const int t = threadIdx.x;

    f16x8 xi = ((const f16x8*)s)[t];
    float v[8];
    #pragma unroll
    for (int j = 0; j < 8; ++j) v[j] = (float)xi[j];

    float mx = v[0];
    #pragma unroll
    for (int j = 1; j < 8; ++j) mx = fmaxf(mx, v[j]);
    #pragma unroll
    for (int o = 32; o; o >>= 1) mx = fmaxf(mx, __shfl_xor(mx, o, 64));
    __shared__ float red[8];
    if ((t & 63) == 0) red[t >> 6] = mx;
    __syncthreads();
    mx = fmaxf(fmaxf(red[0], red[1]), fmaxf(red[2], red[3]));

    float sum = 0.f;
    #pragma unroll
    for (int j = 0; j < 8; ++j) { v[j] = __expf(v[j] - mx); sum += v[j]; }
    #pragma unroll
    for (int o = 32; o; o >>= 1) sum += __shfl_xor(sum, o, 64);
    if ((t & 63) == 0) red[4 + (t >> 6)] = sum;
    __syncthreads();
    sum = (red[4] + red[5]) + (red[6] + red[7]);
    float inv32 = 0.03125f / sum;

    f16x8 o8;
    #pragma unroll
    for (int j = 0; j < 8; ++j) o8[j] = (f16)(v[j] * inv32);
    ((f16x8*)p)[t] = o8;
}

// out[b] = P[b] @ Vt[b]^T  (fp32 out; 1/32 folded into P).
// L2 supertile swizzle: chunks of 2(by) x 4(bx) tiles.
__global__ __launch_bounds__(256) void k_gemm_pv(
    const f16* __restrict__ P, const f16* __restrict__ Vt, float* __restrict__ out)
{
    __shared__ __align__(16) char smem[32768];
    f32x4 acc[4][4];
    const int xcd = blockIdx.x & 7;
    const int idx = blockIdx.x >> 3;        // 0..63
    const int c   = xcd * 8 + idx / 8;      // chunk 0..63
    const int t   = idx % 8;
    const int b   = c >> 4;                 // 0..3
    const int by  = ((c >> 1) & 7) * 2 + t / 4;   // 0..15
    const int bx  = (c & 1) * 4 + t % 4;          // 0..7
    const f16* Pb  = P  + (size_t)b * SEQ * SEQ;
    const f16* Vtb = Vt + (size_t)b * 1024 * SEQ;
    gemm_tile((const char*)(Pb  + (size_t)by * 128 * SEQ),
              (const char*)(Vtb + (size_t)bx * 128 * SEQ),
              SEQ, SEQ, SEQ / 64, smem, acc);

    float* ob = out + (size_t)b * SEQ * 1024;
    const int lane = threadIdx.x & 63;
    const int wave = threadIdx.x >> 6;
    const int row0 = by * 128 + (wave >> 1) * 64;
    const int col0 = bx * 128 + (wave & 1) * 64;
    #pragma unroll
    for (int m = 0; m < 4; ++m)
        #pragma unroll
        for (int n = 0; n < 4; ++n) {
            int col = col0 + n * 16 + (lane & 15);
            #pragma unroll
            for (int j = 0; j < 4; ++j) {
                int row = row0 + m * 16 + (lane >> 4) * 4 + j;
                ob[(size_t)row * 1024 + col] = acc[m][n][j];
            }
        }
}

// ---------- launch ----------

extern "C" void kernel_launch(void* const* d_in, const int* in_sizes, int n_in,
                              void* d_out, int out_size, void* d_ws, size_t ws_size,
                              hipStream_t stream) {
    const float* x  = (const float*)d_in[0];
    const float* Wq = (const float*)d_in[1];
    const float* bq = (const float*)d_in[2];
    const float* Wk = (const float*)d_in[3];
    const float* bk = (const float*)d_in[4];
    const float* Wv = (const float*)d_in[5];
    const float* bv = (const float*)d_in[6];
    float* out = (float*)d_out;
    char* ws = (char*)d_ws;

    // workspace layout (MB offsets):
    //  [0,16)   Q        (P overlays after scores are consumed)
    //  [16,32)  K
    //  [32,48)  Vt       (written directly by the V-proj epilogue)
    //  [48,64)  xh       (dead after V-proj gemm)
    //  [64,70)  wt       (dead after V-proj gemm)
    //  [48,80)  S        f16 scores (32 MB), overlays xh+wt
    f16*  Q  = (f16*)(ws);
    f16*  K  = (f16*)(ws + (size_t)16 * MB);
    f16*  Vt = (f16*)(ws + (size_t)32 * MB);
    f16*  xh = (f16*)(ws + (size_t)48 * MB);
    f16*  wt = (f16*)(ws + (size_t)64 * MB);
    f16*  S  = (f16*)(ws + (size_t)48 * MB);
    f16*  P  = Q;  // overlays dead Q

    const size_t needed = (size_t)80 * MB;
    if (ws_size < needed) return;

    hipFuncSetAttribute((const void*)k_gemm_qk8,
                        hipFuncAttributeMaxDynamicSharedMemorySize, 131072);
    hipFuncSetAttribute((const void*)k_gemm_scores8,
                        hipFuncAttributeMaxDynamicSharedMemorySize, 131072);

    k_prep<<<5120, 256, 0, stream>>>(x, xh, Wq, Wk, Wv, wt);
    k_gemm_qk8<<<256, 512, 131072, stream>>>(xh, wt, bq, bk, Q, K);
    k_gemm_v<<<512, 256, 0, stream>>>(xh, wt + (size_t)2048 * DIN, bv, Vt);
    k_gemm_scores8<<<256, 512, 131072, stream>>>(Q, K, S);
    k_softmax<<<NB * SEQ, 256, 0, stream>>>(S, P);
    k_gemm_pv<<<512, 256, 0, stream>>>(P, Vt, out);
}

// Round 15
// 161.811 us; speedup vs baseline: 1.0131x; 1.0131x over previous
//
#include <hip/hip_runtime.h>
#include <stdint.h>

typedef unsigned short u16;
typedef _Float16 f16;
typedef _Float16 f16x8 __attribute__((ext_vector_type(8)));
typedef float f32x4 __attribute__((ext_vector_type(4)));

#define DIN 1024
#define SEQ 2048
#define NB 4
#define MB (1u << 20)

// ---------- helpers ----------

__device__ __forceinline__ void gload_lds16(const void* g, void* l) {
    __builtin_amdgcn_global_load_lds(
        (__attribute__((address_space(1))) void*)(uintptr_t)g,
        (__attribute__((address_space(3))) void*)l,
        16, 0, 0);
}

__device__ __forceinline__ int xcd_swz(int h, int cpx) {
    return (h & 7) * cpx + (h >> 3);
}

__device__ __forceinline__ void barrier_raw() {
    asm volatile("" ::: "memory");
    __builtin_amdgcn_s_barrier();
    asm volatile("" ::: "memory");
}
template<int N>
__device__ __forceinline__ void wait_lgkm() {
    asm volatile("s_waitcnt lgkmcnt(%0)" :: "i"(N) : "memory");
    __builtin_amdgcn_sched_barrier(0);
}
template<int N>
__device__ __forceinline__ void wait_vm() {
    asm volatile("s_waitcnt vmcnt(%0)" :: "i"(N) : "memory");
}
#define SB0 __builtin_amdgcn_sched_barrier(0)

// ---------- 8-phase 256x256 GEMM mainloop (r14 form; 6 schedule
// variants measured 772-777 TF at K=1024 -- structural plateau) ----------

__device__ __forceinline__ void gemm256(
    const char* __restrict__ A, const char* __restrict__ B,
    int ldab, int ldbb, int nt, char* smem, f32x4 acc[8][4])
{
    const int tid  = threadIdx.x;
    const int lane = tid & 63;
    const int wave = tid >> 6;
    const int ln15 = lane & 15;
    const int k16  = (lane >> 4) << 4;
    const int wmB  = (wave >> 2) * 128;
    const int wnB  = (wave & 3) * 64;

    #pragma unroll
    for (int m = 0; m < 8; ++m)
        #pragma unroll
        for (int n = 0; n < 4; ++n)
            acc[m][n] = (f32x4){0.f, 0.f, 0.f, 0.f};

    const char* pA[2];
    const char* pB[2];
    #pragma unroll
    for (int i = 0; i < 2; ++i) {
        const int La = i * 8192 + tid * 16;
        const int r  = La >> 7;
        const int sc = (La & 127) ^ ((r & 7) << 4);
        pA[i] = A + (size_t)r * ldab + sc;
        pB[i] = B + (size_t)r * ldbb + sc;
    }
    const int ldsw = wave * 1024;

    f16x8 a0[4][2], a1[4][2], b[4][2];

    auto stage = [&](int g) {
        if (g < 4 * nt) {
            const int ks  = g >> 2;
            const int isB = ((g & 2) == 0);
            const int h   = g & 1;
            char* l = smem + (ks & 1) * 65536 + (isB ? 32768 : 0) + h * 16384 + ldsw;
            #pragma unroll
            for (int i = 0; i < 2; ++i) {
                const char* gp = (isB ? pB[i] + (size_t)(h * 128) * ldbb
                                      : pA[i] + (size_t)(h * 128) * ldab) + ks * 128;
                gload_lds16(gp, l + i * 8192);
            }
        }
    };

#define RDA0(base) { _Pragma("unroll") for (int mf = 0; mf < 4; ++mf) { \
        const int r = wmB + mf * 16 + ln15; \
        const int sw = (r & 7) << 4; \
        const char* p = (base) + r * 128; \
        a0[mf][0] = *(const f16x8*)(p + (k16 ^ sw)); \
        a0[mf][1] = *(const f16x8*)(p + ((64 + k16) ^ sw)); } }

#define RDA1H(base, mf0) { _Pragma("unroll") for (int mf = (mf0); mf < (mf0) + 2; ++mf) { \
        const int r = wmB + (mf + 4) * 16 + ln15; \
        const int sw = (r & 7) << 4; \
        const char* p = (base) + r * 128; \
        a1[mf][0] = *(const f16x8*)(p + (k16 ^ sw)); \
        a1[mf][1] = *(const f16x8*)(p + ((64 + k16) ^ sw)); } }

#define RDB2(nf0, base) { _Pragma("unroll") for (int nf = (nf0); nf < (nf0) + 2; ++nf) { \
        const int r = wnB + nf * 16 + ln15; \
        const int sw = (r & 7) << 4; \
        const char* p = (base) + r * 128; \
        b[nf][0] = *(const f16x8*)(p + (k16 ^ sw)); \
        b[nf][1] = *(const f16x8*)(p + ((64 + k16) ^ sw)); } }

#define MM(aa, aoff, nf0) { __builtin_amdgcn_s_setprio(1); \
        _Pragma("unroll") for (int mf = 0; mf < 4; ++mf) \
        _Pragma("unroll") for (int nf = (nf0); nf < (nf0) + 2; ++nf) { \
            acc[(aoff) + mf][nf] = __builtin_amdgcn_mfma_f32_16x16x32_f16( \
                aa[mf][0], b[nf][0], acc[(aoff) + mf][nf], 0, 0, 0); \
            acc[(aoff) + mf][nf] = __builtin_amdgcn_mfma_f32_16x16x32_f16( \
                aa[mf][1], b[nf][1], acc[(aoff) + mf][nf], 0, 0, 0); } \
        __builtin_amdgcn_s_setprio(0); }

    #pragma unroll
    for (int g = 0; g < 8; ++g) stage(g);
    wait_vm<8>();
    barrier_raw();
    RDA0(smem); SB0;
    RDB2(0, smem + 32768); SB0;

    for (int t = 0; t < nt; ++t) {
        const char* sAc = smem + (t & 1) * 65536;
        const char* sBc = sAc + 32768;
        const char* sAn = smem + ((t + 1) & 1) * 65536;
        const char* sBn = sAn + 32768;
        const int gb = 4 * (t + 2);

        RDB2(2, sBc); SB0;
        RDA1H(sAc, 0); SB0;
        barrier_raw(); wait_lgkm<8>(); MM(a0, 0, 0); barrier_raw();

        RDA1H(sAc, 2); SB0;
        barrier_raw(); wait_lgkm<8>(); MM(a0, 0, 2); barrier_raw();

        stage(gb + 0); stage(gb + 1);
        if (t < nt - 2) { wait_vm<4>(); } else if (t == nt - 2) { wait_vm<0>(); }
        barrier_raw(); wait_lgkm<0>(); MM(a1, 4, 0); barrier_raw();

        RDA0(sAn); SB0;
        RDB2(0, sBn); SB0;
        stage(gb + 2); stage(gb + 3);
        barrier_raw(); MM(a1, 4, 2); barrier_raw();
    }
#undef RDA0
#undef RDA1H
#undef RDB2
#undef MM
}

// ---------- LDS-bounce coalesced f16 epilogue for gemm256 users ----------
// acc's native store pattern is 2B column-strided (32B partial-line
// segments -> WRITE_SIZE 44.6MB for 32MB payload, 128 store insts/wave).
// Bounce through the wave's (now free) 16KB LDS slice, XOR-swizzled,
// then store 8-lane x 16B = 128B FULL LINES (16 insts/wave, no RMW).
// bias==nullptr skips the bias add. dst stride in f16 elements.
__device__ __forceinline__ void epilogue_f16(
    f32x4 acc[8][4], char* smem, f16* dst, int dstride,
    int row0, int colb, const float* bias)
{
    const int lane = threadIdx.x & 63;
    const int wave = threadIdx.x >> 6;
    const int ln15 = lane & 15;
    char* eps = smem + wave * 16384;   // [128 rows][128 B]

    barrier_raw(); wait_lgkm<0>();     // drain stale prefetch ds_reads

    const int qrow = (lane >> 4) * 4;
    #pragma unroll
    for (int n = 0; n < 4; ++n) {
        const float bv = bias ? bias[colb + n * 16 + ln15] : 0.0f;
        #pragma unroll
        for (int m = 0; m < 8; ++m) {
            #pragma unroll
            for (int j = 0; j < 4; ++j) {
                const int rl = m * 16 + qrow + j;
                const int cb = (n * 16 + ln15) * 2;
                *(f16*)(eps + rl * 128 + (cb ^ ((rl & 7) << 4))) =
                    (f16)(acc[m][n][j] + bv);
            }
        }
    }
    wait_lgkm<0>();
    #pragma unroll
    for (int i = 0; i < 16; ++i) {
        const int rl = i * 8 + (lane >> 3);
        const int cb = (lane & 7) * 16;
        f16x8 v = *(const f16x8*)(eps + rl * 128 + (cb ^ ((rl & 7) << 4)));
        *(f16x8*)&dst[(size_t)(row0 + rl) * dstride + colb + (lane & 7) * 8] = v;
    }
}

// ---------- 128x128 2-phase mainloop (V-proj + PV) ----------

__device__ __forceinline__ void gemm_tile(
    const char* __restrict__ A, const char* __restrict__ B,
    int lda, int ldb, int ksteps, char* smem, f32x4 acc[4][4])
{
    const int lane = threadIdx.x & 63;
    const int wave = threadIdx.x >> 6;

    #pragma unroll
    for (int m = 0; m < 4; ++m)
        #pragma unroll
        for (int n = 0; n < 4; ++n)
            acc[m][n] = (f32x4){0.f, 0.f, 0.f, 0.f};

    const char* ga[4];
    const char* gb[4];
    int ldsoff[4];
    #pragma unroll
    for (int i = 0; i < 4; ++i) {
        int La = (wave * 4 + i) * 1024 + lane * 16;
        int r  = La >> 7;
        int cb = La & 127;
        int sc = cb ^ ((r & 7) << 4);
        ga[i] = A + (size_t)r * (size_t)(lda * 2) + sc;
        gb[i] = B + (size_t)r * (size_t)(ldb * 2) + sc;
        ldsoff[i] = (wave * 4 + i) * 1024;
    }

    const int wr = (wave >> 1) * 64;
    const int wc = (wave & 1) * 64;

    for (int ks = 0; ks < ksteps; ++ks) {
        #pragma unroll
        for (int i = 0; i < 4; ++i) {
            gload_lds16(ga[i], smem + ldsoff[i]);
            gload_lds16(gb[i], smem + 16384 + ldsoff[i]);
            ga[i] += 128;
            gb[i] += 128;
        }
        __syncthreads();

        #pragma unroll
        for (int kk = 0; kk < 2; ++kk) {
            const int kb = kk * 64 + ((lane >> 4) << 4);
            f16x8 af[4], bfv[4];
            #pragma unroll
            for (int m = 0; m < 4; ++m) {
                int r = wr + m * 16 + (lane & 15);
                af[m] = *(const f16x8*)(smem + r * 128 + (kb ^ ((r & 7) << 4)));
            }
            #pragma unroll
            for (int n = 0; n < 4; ++n) {
                int r = wc + n * 16 + (lane & 15);
                bfv[n] = *(const f16x8*)(smem + 16384 + r * 128 + (kb ^ ((r & 7) << 4)));
            }
            #pragma unroll
            for (int m = 0; m < 4; ++m)
                #pragma unroll
                for (int n = 0; n < 4; ++n)
                    acc[m][n] = __builtin_amdgcn_mfma_f32_16x16x32_f16(
                        af[m], bfv[n], acc[m][n], 0, 0, 0);
        }
        __syncthreads();
    }
}

// ---------- kernels ----------

// Merged prep: blocks [0,2048) convert x fp32->f16; blocks [2048,5120)
// transpose+convert the three W matrices into wt [3*1024(n)][1024(k)] f16.
__global__ __launch_bounds__(256) void k_prep(
    const float* __restrict__ x, f16* __restrict__ xh,
    const float* __restrict__ Wq, const float* __restrict__ Wk,
    const float* __restrict__ Wv, f16* __restrict__ wt)
{
    __shared__ float tile[32][33];
    const int bid = blockIdx.x;
    if (bid < 2048) {
        const int n8 = (NB * SEQ * DIN) / 8;
        for (int idx = bid * 256 + threadIdx.x; idx < n8; idx += 2048 * 256) {
            f32x4 a = ((const f32x4*)x)[(size_t)idx * 2];
            f32x4 b = ((const f32x4*)x)[(size_t)idx * 2 + 1];
            f16x8 o;
            o[0] = (f16)a[0]; o[1] = (f16)a[1]; o[2] = (f16)a[2]; o[3] = (f16)a[3];
            o[4] = (f16)b[0]; o[5] = (f16)b[1]; o[6] = (f16)b[2]; o[7] = (f16)b[3];
            ((f16x8*)xh)[idx] = o;
        }
    } else {
        const int wb = bid - 2048;          // 0..3071
        const int mtx = wb >> 10;           // 0..2
        const int rem = wb & 1023;
        const int n0 = (rem & 31) * 32, k0 = (rem >> 5) * 32;
        const float* W = (mtx == 0) ? Wq : (mtx == 1 ? Wk : Wv);
        const int c = threadIdx.x & 31, r0 = threadIdx.x >> 5;
        #pragma unroll
        for (int rr = r0; rr < 32; rr += 8)
            tile[rr][c] = W[(size_t)(k0 + rr) * DIN + n0 + c];
        __syncthreads();
        f16* o = wt + (size_t)mtx * DIN * DIN;
        #pragma unroll
        for (int rr = r0; rr < 32; rr += 8)
            o[(size_t)(n0 + rr) * DIN + k0 + c] = (f16)tile[c][rr];
    }
}

// Q|K = x @ W^T + bias, 8-phase 256x256, grid 32x8 = 256 (tail-free).
__global__ __launch_bounds__(512, 2) void k_gemm_qk8(
    const f16* __restrict__ xh, const f16* __restrict__ wt,
    const float* __restrict__ bq, const float* __restrict__ bk,
    f16* __restrict__ Q, f16* __restrict__ K)
{
    extern __shared__ char smem[];
    f32x4 acc[8][4];
    const int sid = xcd_swz(blockIdx.x, 32);   // 256 blocks, %8==0
    const int blkN = sid & 7;                  // 0..7  (256-col tiles over Q|K)
    const int blkM = sid >> 3;                 // 0..31
    gemm256((const char*)(xh + (size_t)blkM * 256 * DIN),
            (const char*)(wt + (size_t)blkN * 256 * DIN),
            DIN * 2, DIN * 2, DIN / 64, smem, acc);

    const int wave = threadIdx.x >> 6;
    const int row0 = blkM * 256 + (wave >> 2) * 128;
    const int col0 = blkN * 256 + (wave & 3) * 64;   // wave-uniform matrix id

    f16* dst = (col0 < 1024) ? Q : K;
    const float* bsrc = (col0 < 1024) ? bq : bk;
    epilogue_f16(acc, smem, dst, 1024, row0, col0 & 1023, bsrc);
}

// V = x @ Wv^T + bias, 128x128 2-phase, written TRANSPOSED into Vt[b][d][s].
// Runs BEFORE qk8 this round (tests whether qk8's deficit vs scores8 is a
// first-GEMM-after-prep ordering effect).
__global__ __launch_bounds__(256) void k_gemm_v(
    const f16* __restrict__ xh, const f16* __restrict__ wtv,
    const float* __restrict__ bv, f16* __restrict__ Vt)
{
    __shared__ __align__(16) char smem[32768];
    f32x4 acc[4][4];
    const int sid = xcd_swz(blockIdx.x, 64);   // 512 blocks, %8==0
    const int blkN = sid & 7;                  // 0..7   (V cols)
    const int blkM = sid >> 3;                 // 0..63
    gemm_tile((const char*)(xh  + (size_t)blkM * 128 * DIN),
              (const char*)(wtv + (size_t)blkN * 128 * DIN),
              DIN, DIN, DIN / 64, smem, acc);

    const int lane = threadIdx.x & 63;
    const int wave = threadIdx.x >> 6;
    const int row0 = blkM * 128 + (wave >> 1) * 64;
    const int col0 = blkN * 128 + (wave & 1) * 64;
    const int bb = row0 >> 11;
    const int sb = row0 & (SEQ - 1);
    f16* Vtb = Vt + (size_t)bb * DIN * SEQ;
    #pragma unroll
    for (int n = 0; n < 4; ++n) {
        int d = col0 + n * 16 + (lane & 15);
        float bias = bv[d];
        #pragma unroll
        for (int m = 0; m < 4; ++m) {
            #pragma unroll
            for (int j = 0; j < 4; ++j) {
                int s = sb + m * 16 + (lane >> 4) * 4 + j;
                Vtb[(size_t)d * SEQ + s] = (f16)(acc[m][n][j] + bias);
            }
        }
    }
}

// scores[b] = Q[b] @ K[b]^T, 8-phase 256x256 -> f16 S (unscaled).
__global__ __launch_bounds__(512, 2) void k_gemm_scores8(
    const f16* __restrict__ Q, const f16* __restrict__ K, f16* __restrict__ S)
{
    extern __shared__ char smem[];
    f32x4 acc[8][4];
    const int sid = xcd_swz(blockIdx.x, 32);   // 256 blocks, %8==0
    const int bx = sid & 7, by = (sid >> 3) & 7, b = sid >> 6;
    const f16* Qb = Q + (size_t)b * SEQ * DIN;
    const f16* Kb = K + (size_t)b * SEQ * DIN;
    gemm256((const char*)(Qb + (size_t)by * 256 * DIN),
            (const char*)(Kb + (size_t)bx * 256 * DIN),
            DIN * 2, DIN * 2, DIN / 64, smem, acc);

    f16* Sb = S + (size_t)b * SEQ * SEQ;
    const int wave = threadIdx.x >> 6;
    const int row0 = by * 256 + (wave >> 2) * 128;
    const int col0 = bx * 256 + (wave & 3) * 64;
    epilogue_f16(acc, smem, Sb, SEQ, row0, col0, (const float*)0);
}

// row softmax: one block per row, 2048 f16 in -> 2048 f16 out, /32 folded.
__global__ __launch_bounds__(256) void k_softmax(
    const f16* __restrict__ S, f16* __restrict__ P)
{
    const size_t row = blockIdx.x;
    const f16* s = S + row * SEQ;
    f16* p = P + row * SEQ;
    const int t = threadIdx.x;

    f16x8 xi = ((const f16x8*)s)[t];
    float v[8];
    #pragma unroll
    for (int j = 0; j < 8; ++j) v[j] = (float)xi[j];

    float mx = v[0];
    #pragma unroll
    for (int j = 1; j < 8; ++j) mx = fmaxf(mx, v[j]);
    #pragma unroll
    for (int o = 32; o; o >>= 1) mx = fmaxf(mx, __shfl_xor(mx, o, 64));
    __shared__ float red[8];
    if ((t & 63) == 0) red[t >> 6] = mx;
    __syncthreads();
    mx = fmaxf(fmaxf(red[0], red[1]), fmaxf(red[2], red[3]));

    float sum = 0.f;
    #pragma unroll
    for (int j = 0; j < 8; ++j) { v[j] = __expf(v[j] - mx); sum += v[j]; }
    #pragma unroll
    for (int o = 32; o; o >>= 1) sum += __shfl_xor(sum, o, 64);
    if ((t & 63) == 0) red[4 + (t >> 6)] = sum;
    __syncthreads();
    sum = (red[4] + red[5]) + (red[6] + red[7]);
    float inv32 = 0.03125f / sum;

    f16x8 o8;
    #pragma unroll
    for (int j = 0; j < 8; ++j) o8[j] = (f16)(v[j] * inv32);
    ((f16x8*)p)[t] = o8;
}

// out[b] = P[b] @ Vt[b]^T  (fp32 out; 1/32 folded into P).
// L2 supertile swizzle: chunks of 2(by) x 4(bx) tiles.
__global__ __launch_bounds__(256) void k_gemm_pv(
    const f16* __restrict__ P, const f16* __restrict__ Vt, float* __restrict__ out)
{
    __shared__ __align__(16) char smem[32768];
    f32x4 acc[4][4];
    const int xcd = blockIdx.x & 7;
    const int idx = blockIdx.x >> 3;        // 0..63
    const int c   = xcd * 8 + idx / 8;      // chunk 0..63
    const int t   = idx % 8;
    const int b   = c >> 4;                 // 0..3
    const int by  = ((c >> 1) & 7) * 2 + t / 4;   // 0..15
    const int bx  = (c & 1) * 4 + t % 4;          // 0..7
    const f16* Pb  = P  + (size_t)b * SEQ * SEQ;
    const f16* Vtb = Vt + (size_t)b * 1024 * SEQ;
    gemm_tile((const char*)(Pb  + (size_t)by * 128 * SEQ),
              (const char*)(Vtb + (size_t)bx * 128 * SEQ),
              SEQ, SEQ, SEQ / 64, smem, acc);

    float* ob = out + (size_t)b * SEQ * 1024;
    const int lane = threadIdx.x & 63;
    const int wave = threadIdx.x >> 6;
    const int row0 = by * 128 + (wave >> 1) * 64;
    const int col0 = bx * 128 + (wave & 1) * 64;
    #pragma unroll
    for (int m = 0; m < 4; ++m)
        #pragma unroll
        for (int n = 0; n < 4; ++n) {
            int col = col0 + n * 16 + (lane & 15);
            #pragma unroll
            for (int j = 0; j < 4; ++j) {
                int row = row0 + m * 16 + (lane >> 4) * 4 + j;
                ob[(size_t)row * 1024 + col] = acc[m][n][j];
            }
        }
}

// ---------- launch ----------

extern "C" void kernel_launch(void* const* d_in, const int* in_sizes, int n_in,
                              void* d_out, int out_size, void* d_ws, size_t ws_size,
                              hipStream_t stream) {
    const float* x  = (const float*)d_in[0];
    const float* Wq = (const float*)d_in[1];
    const float* bq = (const float*)d_in[2];
    const float* Wk = (const float*)d_in[3];
    const float* bk = (const float*)d_in[4];
    const float* Wv = (const float*)d_in[5];
    const float* bv = (const float*)d_in[6];
    float* out = (float*)d_out;
    char* ws = (char*)d_ws;

    // workspace layout (MB offsets):
    //  [0,16)   Q        (P overlays after scores are consumed)
    //  [16,32)  K
    //  [32,48)  Vt       (written directly by the V-proj epilogue)
    //  [48,64)  xh       (dead after qk8 gemm)
    //  [64,70)  wt       (dead after qk8 gemm)
    //  [48,80)  S        f16 scores (32 MB), overlays xh+wt
    f16*  Q  = (f16*)(ws);
    f16*  K  = (f16*)(ws + (size_t)16 * MB);
    f16*  Vt = (f16*)(ws + (size_t)32 * MB);
    f16*  xh = (f16*)(ws + (size_t)48 * MB);
    f16*  wt = (f16*)(ws + (size_t)64 * MB);
    f16*  S  = (f16*)(ws + (size_t)48 * MB);
    f16*  P  = Q;  // overlays dead Q

    const size_t needed = (size_t)80 * MB;
    if (ws_size < needed) return;

    hipFuncSetAttribute((const void*)k_gemm_qk8,
                        hipFuncAttributeMaxDynamicSharedMemorySize, 131072);
    hipFuncSetAttribute((const void*)k_gemm_scores8,
                        hipFuncAttributeMaxDynamicSharedMemorySize, 131072);

    k_prep<<<5120, 256, 0, stream>>>(x, xh, Wq, Wk, Wv, wt);
    k_gemm_v<<<512, 256, 0, stream>>>(xh, wt + (size_t)2048 * DIN, bv, Vt);
    k_gemm_qk8<<<256, 512, 131072, stream>>>(xh, wt, bq, bk, Q, K);
    k_gemm_scores8<<<256, 512, 131072, stream>>>(Q, K, S);
    k_softmax<<<NB * SEQ, 256, 0, stream>>>(S, P);
    k_gemm_pv<<<512, 256, 0, stream>>>(P, Vt, out);
}